// Round 3
// baseline (168.470 us; speedup 1.0000x reference)
//
#include <hip/hip_runtime.h>
#include <math.h>

#define NQ 4
#define NL 2

typedef float v2f __attribute__((ext_vector_type(2)));

__device__ __forceinline__ v2f b2(float s) { v2f r; r.x = s; r.y = s; return r; }

__device__ __forceinline__ float fexp2(float x) {
#if __has_builtin(__builtin_amdgcn_exp2f)
    return __builtin_amdgcn_exp2f(x);
#else
    return __expf(0.6931471805599453f * x);
#endif
}

// tanh(x) = 1 - 2/(2^(2*log2e*x)+1), packed over a row-pair
__device__ __forceinline__ v2f tanh2(v2f x) {
    v2f t = x * 2.885390081777927f;            // one v_pk_mul_f32
    v2f e; e.x = fexp2(t.x); e.y = fexp2(t.y); // two v_exp_f32
    v2f d = e + 1.0f;                          // one v_pk_add_f32
    v2f r; r.x = __builtin_amdgcn_rcpf(d.x); r.y = __builtin_amdgcn_rcpf(d.y);
    return __builtin_elementwise_fma(b2(-2.0f), r, b2(1.0f)); // one v_pk_fma_f32
}

extern "C" __global__ void __launch_bounds__(256)
hybrid_pinn_kernel(const float* __restrict__ x,
                   const float* __restrict__ ew1, const float* __restrict__ eb1,
                   const float* __restrict__ ew2, const float* __restrict__ eb2,
                   const float* __restrict__ pw,  const float* __restrict__ pb,
                   const float* __restrict__ qw,
                   const float* __restrict__ pw1, const float* __restrict__ pb1,
                   const float* __restrict__ pw2, const float* __restrict__ pb2,
                   float* __restrict__ out, int rows)
{
    const int pair = blockIdx.x * blockDim.x + threadIdx.x;
    const int row0 = pair * 2;
    if (row0 >= rows) return;

    // two rows' inputs: x[(row0..row0+1), 0..1] = 4 contiguous floats
    const float4 xv = reinterpret_cast<const float4*>(x)[pair];
    v2f xa; xa.x = xv.x; xa.y = xv.z;   // feature 0 of rows (a,b)
    v2f xb; xb.x = xv.y; xb.y = xv.w;   // feature 1 of rows (a,b)

    // ---- encoder layer1 (2->64,tanh) fused into layer2 (64->16) accumulation ----
    v2f z2[16];
#pragma unroll
    for (int j = 0; j < 16; ++j) z2[j] = b2(eb2[j]);
#pragma unroll
    for (int i = 0; i < 64; ++i) {
        v2f a = __builtin_elementwise_fma(
                    xb, b2(ew1[64 + i]),
                    __builtin_elementwise_fma(xa, b2(ew1[i]), b2(eb1[i])));
        v2f z1i = tanh2(a);
#pragma unroll
        for (int j = 0; j < 16; ++j)
            z2[j] = __builtin_elementwise_fma(z1i, b2(ew2[i * 16 + j]), z2[j]);
    }
#pragma unroll
    for (int j = 0; j < 16; ++j) z2[j] = tanh2(z2[j]);

    // ---- pre: 16 -> 4 ----
    v2f qin[NQ];
#pragma unroll
    for (int j = 0; j < NQ; ++j) qin[j] = b2(pb[j]);
#pragma unroll
    for (int i = 0; i < 16; ++i) {
#pragma unroll
        for (int j = 0; j < NQ; ++j)
            qin[j] = __builtin_elementwise_fma(z2[i], b2(pw[i * NQ + j]), qin[j]);
    }

    // ---- quantum circuit: 16-dim real statevector (pair of rows) ----
    v2f cq[NQ], sq[NQ];
#pragma unroll
    for (int q = 0; q < NQ; ++q) {
        v2f half = qin[q] * 0.5f;
        float s0, c0, s1, c1;
        __sincosf(half.x, &s0, &c0);
        __sincosf(half.y, &s1, &c1);
        sq[q].x = s0; sq[q].y = s1;
        cq[q].x = c0; cq[q].y = c1;
    }

    // product state |psi> = RY(a0)..RY(a3)|0000>, qubit q -> bit (8>>q)
    v2f st[16];
#pragma unroll
    for (int i = 0; i < 16; ++i) {
        v2f v = ((i & 8) ? sq[0] : cq[0]);
        v = v * ((i & 4) ? sq[1] : cq[1]);
        v = v * ((i & 2) ? sq[2] : cq[2]);
        v = v * ((i & 1) ? sq[3] : cq[3]);
        st[i] = v;
    }

#pragma unroll
    for (int l = 0; l < NL; ++l) {
        // uniform-angle RY per qubit (wave-uniform cos/sin)
#pragma unroll
        for (int q = 0; q < NQ; ++q) {
            float half = 0.5f * qw[l * NQ + q];
            float cc = __cosf(half);
            float ss = __sinf(half);
            const int bit = 8 >> q;
#pragma unroll
            for (int i = 0; i < 16; ++i) {
                if (i & bit) continue;
                v2f a0 = st[i], a1 = st[i | bit];
                v2f ms = b2(-ss) * a1;
                st[i]       = __builtin_elementwise_fma(b2(cc), a0, ms);
                v2f cs = b2(cc) * a1;
                st[i | bit] = __builtin_elementwise_fma(b2(ss), a0, cs);
            }
        }
        // CNOT ring: compile-time register permutation
        const int cn[4][2] = {{8, 4}, {4, 2}, {2, 1}, {1, 8}};
#pragma unroll
        for (int k = 0; k < 4; ++k) {
            const int bc = cn[k][0], bt = cn[k][1];
#pragma unroll
            for (int i = 0; i < 16; ++i) {
                if ((i & bc) && !(i & bt)) {
                    v2f t = st[i];
                    st[i] = st[i | bt];
                    st[i | bt] = t;
                }
            }
        }
    }

    // probabilities + Z expectations
    v2f p[16];
#pragma unroll
    for (int i = 0; i < 16; ++i) p[i] = st[i] * st[i];

    v2f qo[NQ];
#pragma unroll
    for (int q = 0; q < NQ; ++q) {
        const int bit = 8 >> q;
        v2f acc = b2(0.0f);
#pragma unroll
        for (int i = 0; i < 16; ++i)
            acc = acc + ((i & bit) ? -p[i] : p[i]);
        qo[q] = acc;
    }

    // ---- post layer1: 4 -> 32, tanh ----
    v2f h[32];
#pragma unroll
    for (int j = 0; j < 32; ++j) {
        v2f a = b2(pb1[j]);
#pragma unroll
        for (int i = 0; i < NQ; ++i)
            a = __builtin_elementwise_fma(qo[i], b2(pw1[i * 32 + j]), a);
        h[j] = tanh2(a);
    }

    // ---- post layer2: 32 -> 4 ----
    v2f o[4];
#pragma unroll
    for (int j = 0; j < 4; ++j) o[j] = b2(pb2[j]);
#pragma unroll
    for (int i = 0; i < 32; ++i) {
#pragma unroll
        for (int j = 0; j < 4; ++j)
            o[j] = __builtin_elementwise_fma(h[i], b2(pw2[i * 4 + j]), o[j]);
    }

    // two adjacent float4 rows
    float4* outv = reinterpret_cast<float4*>(out);
    outv[row0]     = make_float4(o[0].x, o[1].x, o[2].x, o[3].x);
    outv[row0 + 1] = make_float4(o[0].y, o[1].y, o[2].y, o[3].y);
}

extern "C" void kernel_launch(void* const* d_in, const int* in_sizes, int n_in,
                              void* d_out, int out_size, void* d_ws, size_t ws_size,
                              hipStream_t stream) {
    const float* x   = (const float*)d_in[0];
    const float* ew1 = (const float*)d_in[1];
    const float* eb1 = (const float*)d_in[2];
    const float* ew2 = (const float*)d_in[3];
    const float* eb2 = (const float*)d_in[4];
    const float* pw  = (const float*)d_in[5];
    const float* pb  = (const float*)d_in[6];
    const float* qw  = (const float*)d_in[7];
    const float* pw1 = (const float*)d_in[8];
    const float* pb1 = (const float*)d_in[9];
    const float* pw2 = (const float*)d_in[10];
    const float* pb2 = (const float*)d_in[11];
    float* out = (float*)d_out;

    const int rows = in_sizes[0] / 2;
    const int pairs = rows / 2;
    const int block = 256;
    const int grid = (pairs + block - 1) / block;

    hipLaunchKernelGGL(hybrid_pinn_kernel, dim3(grid), dim3(block), 0, stream,
                       x, ew1, eb1, ew2, eb2, pw, pb, qw,
                       pw1, pb1, pw2, pb2, out, rows);
}

// Round 4
// 34.263 us; speedup vs baseline: 4.9169x; 4.9169x over previous
//
#include <hip/hip_runtime.h>
#include <math.h>

#define NQ 4
#define NL 2

typedef _Float16 f16;
typedef _Float16 f16x8 __attribute__((ext_vector_type(8)));
typedef float f32x4 __attribute__((ext_vector_type(4)));

__device__ __forceinline__ float fast_tanh(float x) {
    // tanh(x) = 1 - 2/(exp(2x)+1)
    float e = __expf(x + x);
    float r = __builtin_amdgcn_rcpf(e + 1.0f);
    return fmaf(-2.0f, r, 1.0f);
}

// LDS: z1 staging (f16, pitch 72 = 144B) overlaid by z2 (f32, pitch 20 = 80B)
__shared__ union SMem {
    f16   z1[256][72];   // 36864 B
    float z2[256][20];   // 20480 B
} sm_u;

extern "C" __global__ void __launch_bounds__(256)
hybrid_pinn_kernel(const float* __restrict__ x,
                   const float* __restrict__ ew1, const float* __restrict__ eb1,
                   const float* __restrict__ ew2, const float* __restrict__ eb2,
                   const float* __restrict__ pw,  const float* __restrict__ pb,
                   const float* __restrict__ qw,
                   const float* __restrict__ pw1, const float* __restrict__ pb1,
                   const float* __restrict__ pw2, const float* __restrict__ pb2,
                   float* __restrict__ out, int rows)
{
    const int tid  = threadIdx.x;            // block-local row
    const int lane = tid & 63;
    const int wbase = (tid >> 6) * 64;       // wave's first block-local row
    const int row  = blockIdx.x * 256 + tid; // global row (rows % 256 == 0)

    // ---- B-fragments of ew2 (64x16) as f16, loaded once per thread ----
    // B[k][n]: lane holds col n = lane&15, k = kt*32 + (lane>>4)*8 + j
    const int bn = lane & 15;
    const int bk0 = (lane >> 4) * 8;
    f16x8 bfrag0, bfrag1;
#pragma unroll
    for (int j = 0; j < 8; ++j) {
        bfrag0[j] = (f16)ew2[(bk0 + j) * 16 + bn];
        bfrag1[j] = (f16)ew2[(32 + bk0 + j) * 16 + bn];
    }

    // ---- layer1: 2 -> 64, tanh; stage z1 row to LDS as f16 ----
    const float2 xv = reinterpret_cast<const float2*>(x)[row];
#pragma unroll
    for (int c = 0; c < 8; ++c) {
        f16x8 pack;
#pragma unroll
        for (int j = 0; j < 8; ++j) {
            const int i = c * 8 + j;
            float a = fmaf(xv.y, ew1[64 + i], fmaf(xv.x, ew1[i], eb1[i]));
            pack[j] = (f16)fast_tanh(a);
        }
        *reinterpret_cast<f16x8*>(&sm_u.z1[tid][c * 8]) = pack;
    }
    __syncthreads();

    // ---- A-fragments: 4 m-tiles x 2 k-tiles per wave ----
    // A[m][k]: lane holds row m = mt*16 + (lane&15), k = kt*32 + (lane>>4)*8 + j
    const int ar = wbase + (lane & 15);
    const int ak = (lane >> 4) * 8;
    f16x8 afrag[4][2];
#pragma unroll
    for (int mt = 0; mt < 4; ++mt) {
#pragma unroll
        for (int kt = 0; kt < 2; ++kt)
            afrag[mt][kt] = *reinterpret_cast<const f16x8*>(
                &sm_u.z1[ar + mt * 16][kt * 32 + ak]);
    }
    __syncthreads();   // all waves done reading z1 -> safe to overlay with z2

    // ---- 8 MFMAs: z2_pre[64 rows][16] per wave ----
    f32x4 acc[4];
#pragma unroll
    for (int mt = 0; mt < 4; ++mt) {
        f32x4 z = {0.f, 0.f, 0.f, 0.f};
        z = __builtin_amdgcn_mfma_f32_16x16x32_f16(afrag[mt][0], bfrag0, z, 0, 0, 0);
        z = __builtin_amdgcn_mfma_f32_16x16x32_f16(afrag[mt][1], bfrag1, z, 0, 0, 0);
        acc[mt] = z;
    }
    // C layout: col = lane&15, row = mt*16 + (lane>>4)*4 + j
#pragma unroll
    for (int mt = 0; mt < 4; ++mt) {
#pragma unroll
        for (int j = 0; j < 4; ++j)
            sm_u.z2[wbase + mt * 16 + (lane >> 4) * 4 + j][lane & 15] = acc[mt][j];
    }
    __syncthreads();

    // ---- read own row's z2, bias + tanh ----
    float z2[16];
    {
        float4 r0 = *reinterpret_cast<const float4*>(&sm_u.z2[tid][0]);
        float4 r1 = *reinterpret_cast<const float4*>(&sm_u.z2[tid][4]);
        float4 r2 = *reinterpret_cast<const float4*>(&sm_u.z2[tid][8]);
        float4 r3 = *reinterpret_cast<const float4*>(&sm_u.z2[tid][12]);
        z2[0]=r0.x; z2[1]=r0.y; z2[2]=r0.z; z2[3]=r0.w;
        z2[4]=r1.x; z2[5]=r1.y; z2[6]=r1.z; z2[7]=r1.w;
        z2[8]=r2.x; z2[9]=r2.y; z2[10]=r2.z; z2[11]=r2.w;
        z2[12]=r3.x; z2[13]=r3.y; z2[14]=r3.z; z2[15]=r3.w;
    }
#pragma unroll
    for (int j = 0; j < 16; ++j) z2[j] = fast_tanh(z2[j] + eb2[j]);

    // ---- pre: 16 -> 4 ----
    float qin[NQ];
#pragma unroll
    for (int j = 0; j < NQ; ++j) qin[j] = pb[j];
#pragma unroll
    for (int i = 0; i < 16; ++i) {
        float zi = z2[i];
#pragma unroll
        for (int j = 0; j < NQ; ++j)
            qin[j] = fmaf(zi, pw[i * NQ + j], qin[j]);
    }

    // ---- quantum circuit: 16-dim real statevector ----
    float cq[NQ], sq[NQ];
#pragma unroll
    for (int q = 0; q < NQ; ++q)
        __sincosf(0.5f * qin[q], &sq[q], &cq[q]);

    float st[16];
#pragma unroll
    for (int i = 0; i < 16; ++i) {
        float v = ((i & 8) ? sq[0] : cq[0]);
        v *= ((i & 4) ? sq[1] : cq[1]);
        v *= ((i & 2) ? sq[2] : cq[2]);
        v *= ((i & 1) ? sq[3] : cq[3]);
        st[i] = v;
    }

#pragma unroll
    for (int l = 0; l < NL; ++l) {
#pragma unroll
        for (int q = 0; q < NQ; ++q) {
            float half = 0.5f * qw[l * NQ + q];
            float cc = __cosf(half);
            float ss = __sinf(half);
            const int bit = 8 >> q;
#pragma unroll
            for (int i = 0; i < 16; ++i) {
                if (i & bit) continue;
                float a0 = st[i], a1 = st[i | bit];
                st[i]       = fmaf(cc, a0, -ss * a1);
                st[i | bit] = fmaf(ss, a0,  cc * a1);
            }
        }
        const int cn[4][2] = {{8, 4}, {4, 2}, {2, 1}, {1, 8}};
#pragma unroll
        for (int k = 0; k < 4; ++k) {
            const int bc = cn[k][0], bt = cn[k][1];
#pragma unroll
            for (int i = 0; i < 16; ++i) {
                if ((i & bc) && !(i & bt)) {
                    float t = st[i];
                    st[i] = st[i | bt];
                    st[i | bt] = t;
                }
            }
        }
    }

    float p[16];
#pragma unroll
    for (int i = 0; i < 16; ++i) p[i] = st[i] * st[i];

    float qo[NQ];
#pragma unroll
    for (int q = 0; q < NQ; ++q) {
        const int bit = 8 >> q;
        float acc2 = 0.0f;
#pragma unroll
        for (int i = 0; i < 16; ++i)
            acc2 += (i & bit) ? -p[i] : p[i];
        qo[q] = acc2;
    }

    // ---- post layer1: 4 -> 32, tanh ----
    float h[32];
#pragma unroll
    for (int j = 0; j < 32; ++j) {
        float a = pb1[j];
#pragma unroll
        for (int i = 0; i < NQ; ++i)
            a = fmaf(qo[i], pw1[i * 32 + j], a);
        h[j] = fast_tanh(a);
    }

    // ---- post layer2: 32 -> 4 ----
    float o[4];
#pragma unroll
    for (int j = 0; j < 4; ++j) o[j] = pb2[j];
#pragma unroll
    for (int i = 0; i < 32; ++i) {
        float hi = h[i];
#pragma unroll
        for (int j = 0; j < 4; ++j)
            o[j] = fmaf(hi, pw2[i * 4 + j], o[j]);
    }

    reinterpret_cast<float4*>(out)[row] = make_float4(o[0], o[1], o[2], o[3]);
}

extern "C" void kernel_launch(void* const* d_in, const int* in_sizes, int n_in,
                              void* d_out, int out_size, void* d_ws, size_t ws_size,
                              hipStream_t stream) {
    const float* x   = (const float*)d_in[0];
    const float* ew1 = (const float*)d_in[1];
    const float* eb1 = (const float*)d_in[2];
    const float* ew2 = (const float*)d_in[3];
    const float* eb2 = (const float*)d_in[4];
    const float* pw  = (const float*)d_in[5];
    const float* pb  = (const float*)d_in[6];
    const float* qw  = (const float*)d_in[7];
    const float* pw1 = (const float*)d_in[8];
    const float* pb1 = (const float*)d_in[9];
    const float* pw2 = (const float*)d_in[10];
    const float* pb2 = (const float*)d_in[11];
    float* out = (float*)d_out;

    const int rows = in_sizes[0] / 2;   // 524288, multiple of 256
    const int block = 256;
    const int grid = rows / block;

    hipLaunchKernelGGL(hybrid_pinn_kernel, dim3(grid), dim3(block), 0, stream,
                       x, ew1, eb1, ew2, eb2, pw, pb, qw,
                       pw1, pb1, pw2, pb2, out, rows);
}

// Round 6
// 29.756 us; speedup vs baseline: 5.6617x; 1.1515x over previous
//
#include <hip/hip_runtime.h>
#include <math.h>

#define NQ 4
#define NL 2

typedef _Float16 f16;
typedef _Float16 f16x8 __attribute__((ext_vector_type(8)));
typedef float f32x4 __attribute__((ext_vector_type(4)));

__device__ __forceinline__ float fast_tanh(float x) {
    // tanh(x) = 1 - 2/(2^(2*log2e*x)+1)
    float e = __builtin_amdgcn_exp2f(x * 2.885390081777927f);
    float r = __builtin_amdgcn_rcpf(e + 1.0f);
    return fmaf(-2.0f, r, 1.0f);
}

// only the z2 transpose lives in LDS now: 256 rows x 16 cols, pitch 20 f32
__shared__ float z2s[256][20];

extern "C" __global__ void __launch_bounds__(256)
hybrid_pinn_kernel(const float* __restrict__ x,
                   const float* __restrict__ ew1, const float* __restrict__ eb1,
                   const float* __restrict__ ew2, const float* __restrict__ eb2,
                   const float* __restrict__ pw,  const float* __restrict__ pb,
                   const float* __restrict__ qw,
                   const float* __restrict__ pw1, const float* __restrict__ pb1,
                   const float* __restrict__ pw2, const float* __restrict__ pb2,
                   float* __restrict__ out, int rows)
{
    const int tid   = threadIdx.x;
    const int lane  = tid & 63;
    const int wbase = (tid >> 6) * 64;        // wave's first block-local row
    const int brow0 = blockIdx.x * 256;       // block's first global row

    // ---- B-fragments of ew2 (64x16) as f16 ----
    // B[k][n]: lane holds col n = lane&15, k = kt*32 + (lane>>4)*8 + j
    const int bn  = lane & 15;
    const int ak  = (lane >> 4) * 8;
    f16x8 bfrag0, bfrag1;
#pragma unroll
    for (int j = 0; j < 8; ++j) {
        bfrag0[j] = (f16)ew2[(ak + j) * 16 + bn];
        bfrag1[j] = (f16)ew2[(32 + ak + j) * 16 + bn];
    }

    // ---- x rows this lane's A-fragments cover: rows wbase + (lane&15) + mt*16 ----
    const float2* x2 = reinterpret_cast<const float2*>(x);
    float2 xr[4];
#pragma unroll
    for (int mt = 0; mt < 4; ++mt)
        xr[mt] = x2[brow0 + wbase + (lane & 15) + mt * 16];

    // ---- layer-1 weight slices for this lane's 16 features: f = kt*32 + ak + j ----
    float w0[16], w1[16], bb[16];
#pragma unroll
    for (int kt = 0; kt < 2; ++kt) {
        const int base = kt * 32 + ak;        // multiple of 8 -> 32B aligned
        *reinterpret_cast<float4*>(&w0[kt * 8])     = *reinterpret_cast<const float4*>(&ew1[base]);
        *reinterpret_cast<float4*>(&w0[kt * 8 + 4]) = *reinterpret_cast<const float4*>(&ew1[base + 4]);
        *reinterpret_cast<float4*>(&w1[kt * 8])     = *reinterpret_cast<const float4*>(&ew1[64 + base]);
        *reinterpret_cast<float4*>(&w1[kt * 8 + 4]) = *reinterpret_cast<const float4*>(&ew1[64 + base + 4]);
        *reinterpret_cast<float4*>(&bb[kt * 8])     = *reinterpret_cast<const float4*>(&eb1[base]);
        *reinterpret_cast<float4*>(&bb[kt * 8 + 4]) = *reinterpret_cast<const float4*>(&eb1[base + 4]);
    }

    // ---- A-fragments computed directly: z1[row][feature] = tanh(layer1) ----
    f16x8 afrag[4][2];
#pragma unroll
    for (int mt = 0; mt < 4; ++mt) {
#pragma unroll
        for (int kt = 0; kt < 2; ++kt) {
#pragma unroll
            for (int j = 0; j < 8; ++j) {
                const int f = kt * 8 + j;
                float a = fmaf(xr[mt].y, w1[f], fmaf(xr[mt].x, w0[f], bb[f]));
                afrag[mt][kt][j] = (f16)fast_tanh(a);
            }
        }
    }

    // ---- 8 MFMAs: z2_pre[64 rows][16] per wave ----
    f32x4 acc[4];
#pragma unroll
    for (int mt = 0; mt < 4; ++mt) {
        f32x4 z = {0.f, 0.f, 0.f, 0.f};
        z = __builtin_amdgcn_mfma_f32_16x16x32_f16(afrag[mt][0], bfrag0, z, 0, 0, 0);
        z = __builtin_amdgcn_mfma_f32_16x16x32_f16(afrag[mt][1], bfrag1, z, 0, 0, 0);
        acc[mt] = z;
    }
    // C layout: col = lane&15, row = mt*16 + (lane>>4)*4 + j
#pragma unroll
    for (int mt = 0; mt < 4; ++mt) {
#pragma unroll
        for (int j = 0; j < 4; ++j)
            z2s[wbase + mt * 16 + (lane >> 4) * 4 + j][lane & 15] = acc[mt][j];
    }
    __syncthreads();

    // ---- read own row's z2, bias + tanh ----
    float z2[16];
    {
        float4 r0 = *reinterpret_cast<const float4*>(&z2s[tid][0]);
        float4 r1 = *reinterpret_cast<const float4*>(&z2s[tid][4]);
        float4 r2 = *reinterpret_cast<const float4*>(&z2s[tid][8]);
        float4 r3 = *reinterpret_cast<const float4*>(&z2s[tid][12]);
        z2[0]=r0.x; z2[1]=r0.y; z2[2]=r0.z; z2[3]=r0.w;
        z2[4]=r1.x; z2[5]=r1.y; z2[6]=r1.z; z2[7]=r1.w;
        z2[8]=r2.x; z2[9]=r2.y; z2[10]=r2.z; z2[11]=r2.w;
        z2[12]=r3.x; z2[13]=r3.y; z2[14]=r3.z; z2[15]=r3.w;
    }
#pragma unroll
    for (int j = 0; j < 16; ++j) z2[j] = fast_tanh(z2[j] + eb2[j]);

    // ---- pre: 16 -> 4 ----
    float qin[NQ];
#pragma unroll
    for (int j = 0; j < NQ; ++j) qin[j] = pb[j];
#pragma unroll
    for (int i = 0; i < 16; ++i) {
        float zi = z2[i];
#pragma unroll
        for (int j = 0; j < NQ; ++j)
            qin[j] = fmaf(zi, pw[i * NQ + j], qin[j]);
    }

    // ---- quantum circuit ----
    float cq[NQ], sq[NQ];
#pragma unroll
    for (int q = 0; q < NQ; ++q)
        __sincosf(0.5f * qin[q], &sq[q], &cq[q]);

    // product state via 2-level tree: bit8->q0, bit4->q1, bit2->q2, bit1->q3
    float ab[4], cd[4];
#pragma unroll
    for (int h = 0; h < 4; ++h) {
        ab[h] = ((h & 2) ? sq[0] : cq[0]) * ((h & 1) ? sq[1] : cq[1]);
        cd[h] = ((h & 2) ? sq[2] : cq[2]) * ((h & 1) ? sq[3] : cq[3]);
    }
    float st[16];
#pragma unroll
    for (int i = 0; i < 16; ++i)
        st[i] = ab[i >> 2] * cd[i & 3];

#pragma unroll
    for (int l = 0; l < NL; ++l) {
#pragma unroll
        for (int q = 0; q < NQ; ++q) {
            float half = 0.5f * qw[l * NQ + q];
            float cc = __cosf(half);
            float ss = __sinf(half);
            const int bit = 8 >> q;
#pragma unroll
            for (int i = 0; i < 16; ++i) {
                if (i & bit) continue;
                float a0 = st[i], a1 = st[i | bit];
                st[i]       = fmaf(cc, a0, -ss * a1);
                st[i | bit] = fmaf(ss, a0,  cc * a1);
            }
        }
        const int cn[4][2] = {{8, 4}, {4, 2}, {2, 1}, {1, 8}};
#pragma unroll
        for (int k = 0; k < 4; ++k) {
            const int bc = cn[k][0], bt = cn[k][1];
#pragma unroll
            for (int i = 0; i < 16; ++i) {
                if ((i & bc) && !(i & bt)) {
                    float t = st[i];
                    st[i] = st[i | bt];
                    st[i | bt] = t;
                }
            }
        }
    }

    // probs + shared-subtree marginal sums
    float p[16];
#pragma unroll
    for (int i = 0; i < 16; ++i) p[i] = st[i] * st[i];

    float e[8], d[8];
#pragma unroll
    for (int i = 0; i < 8; ++i) { e[i] = p[2*i] + p[2*i+1]; d[i] = p[2*i] - p[2*i+1]; }
    float f0 = e[0] + e[1], f1 = e[2] + e[3], f2 = e[4] + e[5], f3 = e[6] + e[7];
    float qo[NQ];
    qo[3] = ((d[0]+d[1]) + (d[2]+d[3])) + ((d[4]+d[5]) + (d[6]+d[7]));
    qo[2] = ((e[0]-e[1]) + (e[2]-e[3])) + ((e[4]-e[5]) + (e[6]-e[7]));
    qo[1] = (f0 - f1) + (f2 - f3);
    qo[0] = (f0 + f1) - (f2 + f3);

    // ---- post layer1: 4 -> 32, tanh ----
    float h[32];
#pragma unroll
    for (int j = 0; j < 32; ++j) {
        float a = pb1[j];
#pragma unroll
        for (int i = 0; i < NQ; ++i)
            a = fmaf(qo[i], pw1[i * 32 + j], a);
        h[j] = fast_tanh(a);
    }

    // ---- post layer2: 32 -> 4 ----
    float o[4];
#pragma unroll
    for (int j = 0; j < 4; ++j) o[j] = pb2[j];
#pragma unroll
    for (int i = 0; i < 32; ++i) {
        float hi = h[i];
#pragma unroll
        for (int j = 0; j < 4; ++j)
            o[j] = fmaf(hi, pw2[i * 4 + j], o[j]);
    }

    reinterpret_cast<float4*>(out)[brow0 + tid] = make_float4(o[0], o[1], o[2], o[3]);
}

extern "C" void kernel_launch(void* const* d_in, const int* in_sizes, int n_in,
                              void* d_out, int out_size, void* d_ws, size_t ws_size,
                              hipStream_t stream) {
    const float* x   = (const float*)d_in[0];
    const float* ew1 = (const float*)d_in[1];
    const float* eb1 = (const float*)d_in[2];
    const float* ew2 = (const float*)d_in[3];
    const float* eb2 = (const float*)d_in[4];
    const float* pw  = (const float*)d_in[5];
    const float* pb  = (const float*)d_in[6];
    const float* qw  = (const float*)d_in[7];
    const float* pw1 = (const float*)d_in[8];
    const float* pb1 = (const float*)d_in[9];
    const float* pw2 = (const float*)d_in[10];
    const float* pb2 = (const float*)d_in[11];
    float* out = (float*)d_out;

    const int rows = in_sizes[0] / 2;   // 524288, multiple of 256
    const int block = 256;
    const int grid = rows / block;

    hipLaunchKernelGGL(hybrid_pinn_kernel, dim3(grid), dim3(block), 0, stream,
                       x, ew1, eb1, ew2, eb2, pw, pb, qw,
                       pw1, pb1, pw2, pb2, out, rows);
}